// Round 5
// baseline (4506.730 us; speedup 1.0000x reference)
//
#include <hip/hip_runtime.h>
#include <math.h>

typedef unsigned short u16;
typedef unsigned int   u32;
typedef __attribute__((ext_vector_type(8))) short bf16x8;   // 8 bf16 = 4 VGPR
typedef __attribute__((ext_vector_type(4))) float f32x4;
typedef __attribute__((ext_vector_type(4))) u16   u16x4;
typedef __attribute__((ext_vector_type(8))) u16   u16x8;

#define MFMA(a,b,c) __builtin_amdgcn_mfma_f32_16x16x32_bf16((a),(b),(c),0,0,0)

__device__ __forceinline__ u16 f2bf(float f) {
    u32 u = __float_as_uint(f);
    u32 r = (u + 0x7fffu + ((u >> 16) & 1u)) >> 16;   // RNE
    return (u16)r;
}
__device__ __forceinline__ float bf2f(u16 h) { return __uint_as_float(((u32)h) << 16); }

// ---------------------------------------------------------------- sincos table
__global__ void sincos_kernel(float* __restrict__ st, float* __restrict__ ct) {
    int idx = blockIdx.x * 256 + threadIdx.x;      // 2048*32
    int t = idx >> 5, j = idx & 31;
    double inv = pow(10000.0, -(double)j / 32.0);
    double a = (double)t * inv;
    st[idx] = (float)sin(a);
    ct[idx] = (float)cos(a);
}

// ---------------------------------------------------------------- layernorm + split
__global__ __launch_bounds__(256) void ln_kernel(
    const float* __restrict__ x, const float* __restrict__ sc,
    const float* __restrict__ ofs, u16* __restrict__ Oh, u16* __restrict__ Ol) {
    const int row = blockIdx.x, tid = threadIdx.x;
    const float* xr = x + (size_t)row * 4096;
    float4 v[4];
    float s1 = 0.f, s2 = 0.f;
#pragma unroll
    for (int i = 0; i < 4; i++) {
        v[i] = *(const float4*)&xr[i * 1024 + tid * 4];
        s1 += v[i].x + v[i].y + v[i].z + v[i].w;
        s2 += v[i].x * v[i].x + v[i].y * v[i].y + v[i].z * v[i].z + v[i].w * v[i].w;
    }
#pragma unroll
    for (int m = 1; m < 64; m <<= 1) { s1 += __shfl_xor(s1, m); s2 += __shfl_xor(s2, m); }
    __shared__ float red[8];
    int w = tid >> 6;
    if ((tid & 63) == 0) { red[w] = s1; red[4 + w] = s2; }
    __syncthreads();
    s1 = red[0] + red[1] + red[2] + red[3];
    s2 = red[4] + red[5] + red[6] + red[7];
    float mean = s1 * (1.0f / 4096.0f);
    float var  = s2 * (1.0f / 4096.0f) - mean * mean;
    float rs   = 1.0f / sqrtf(var + 1e-5f);
#pragma unroll
    for (int i = 0; i < 4; i++) {
        int c0 = i * 1024 + tid * 4;
        float xs[4] = { v[i].x, v[i].y, v[i].z, v[i].w };
        u16x4 hv, lv;
#pragma unroll
        for (int j = 0; j < 4; j++) {
            float xn = sc[c0 + j] * rs * (xs[j] - mean) + ofs[c0 + j];
            u16 hh = f2bf(xn);
            hv[j] = hh;
            lv[j] = f2bf(xn - bf2f(hh));
        }
        *(u16x4*)&Oh[(size_t)row * 4096 + c0] = hv;
        *(u16x4*)&Ol[(size_t)row * 4096 + c0] = lv;
    }
}

// ---------------------------------------------------------------- rope (in-place on split q,k)
// 2048 rows * 16 heads * 32 rotated pairs = 1,048,576 threads
__global__ __launch_bounds__(256) void rope_kernel(
    u16* __restrict__ qh, u16* __restrict__ ql, u16* __restrict__ kh, u16* __restrict__ kl,
    const float* __restrict__ st, const float* __restrict__ ct) {
    int gid = blockIdx.x * 256 + threadIdx.x;
    int t  = gid >> 9;                 // row
    int hh_ = (gid >> 5) & 15;         // head
    int j2 = gid & 31;                 // rotated pair within head
    size_t base = (size_t)t * 4096 + (size_t)hh_ * 256 + (size_t)j2 * 2;
    float s = st[t * 32 + j2], c = ct[t * 32 + j2];
    {
        float x1 = bf2f(qh[base]) + bf2f(ql[base]);
        float x2 = bf2f(qh[base + 1]) + bf2f(ql[base + 1]);
        float o1 = x1 * c - x2 * s, o2 = x2 * c + x1 * s;
        u16 h1 = f2bf(o1); qh[base] = h1;     ql[base] = f2bf(o1 - bf2f(h1));
        u16 h2 = f2bf(o2); qh[base + 1] = h2; ql[base + 1] = f2bf(o2 - bf2f(h2));
    }
    {
        float x1 = bf2f(kh[base]) + bf2f(kl[base]);
        float x2 = bf2f(kh[base + 1]) + bf2f(kl[base + 1]);
        float o1 = x1 * c - x2 * s, o2 = x2 * c + x1 * s;
        u16 h1 = f2bf(o1); kh[base] = h1;     kl[base] = f2bf(o1 - bf2f(h1));
        u16 h2 = f2bf(o2); kh[base + 1] = h2; kl[base + 1] = f2bf(o2 - bf2f(h2));
    }
}

// ---------------------------------------------------------------- GEMM (bf16x3 split, 128x128 tile)
// A: M x K as hi/lo bf16 (pre-split). B: K x N f32 (split on the fly). C = A @ B.
enum { EPI_F32 = 0, EPI_SPLIT = 1, EPI_GELU = 2, EPI_FINAL = 3 };

template <int EPI>
__global__ __launch_bounds__(256, 2) void gemm_kernel(
    const u16* __restrict__ Ah, const u16* __restrict__ Al,
    const float* __restrict__ B, int M, int N, int K,
    float* __restrict__ Cf, u16* __restrict__ Oh, u16* __restrict__ Ol,
    const float* __restrict__ bias, const float* __restrict__ addin) {
    // stride 40 elems (80B): S/4 = 20 == 4 (mod 8) -> 2-way (free) bank pattern on b128 reads
    __shared__ __align__(16) u16 LA[2][128 * 40];
    __shared__ __align__(16) u16 LB[2][128 * 40];   // n-major: [n][k]
    const int tid = threadIdx.x;
    const int lane = tid & 63, w = tid >> 6;
    const int wm = (w >> 1) * 64, wn = (w & 1) * 64;
    const size_t n0 = (size_t)blockIdx.x * 128, m0 = (size_t)blockIdx.y * 128;
    const int fr = lane & 15, g = lane >> 4;
    const int ar = tid >> 2, as = tid & 3;          // A staging: row, 8-elem slot
    const int bkg = tid >> 5, bng = tid & 31;       // B staging: k-group(8 of 4), n-group(32 of 4)
    f32x4 acc[4][4] = {};

    for (int k0 = 0; k0 < K; k0 += 32) {
        __syncthreads();
        // ---- stage A (hi & lo), [row][k] with padded stride
#pragma unroll
        for (int i = 0; i < 2; i++) {
            int row = ar + i * 64;
            size_t gs = (m0 + row) * (size_t)K + k0 + as * 8;
            *(u16x8*)&LA[0][row * 40 + as * 8] = *(const u16x8*)&Ah[gs];
            *(u16x8*)&LA[1][row * 40 + as * 8] = *(const u16x8*)&Al[gs];
        }
        // ---- stage B: 4x4 micro-tile, f32 -> hi/lo, transpose to n-major
        float4 rv[4];
#pragma unroll
        for (int i = 0; i < 4; i++)
            rv[i] = *(const float4*)&B[(size_t)(k0 + bkg * 4 + i) * N + n0 + bng * 4];
#pragma unroll
        for (int j = 0; j < 4; j++) {
            float v0 = (&rv[0].x)[j], v1 = (&rv[1].x)[j], v2 = (&rv[2].x)[j], v3 = (&rv[3].x)[j];
            u16 h0 = f2bf(v0), h1 = f2bf(v1), h2 = f2bf(v2), h3 = f2bf(v3);
            u16x4 hv = { h0, h1, h2, h3 };
            u16x4 lv = { f2bf(v0 - bf2f(h0)), f2bf(v1 - bf2f(h1)),
                         f2bf(v2 - bf2f(h2)), f2bf(v3 - bf2f(h3)) };
            *(u16x4*)&LB[0][(bng * 4 + j) * 40 + bkg * 4] = hv;
            *(u16x4*)&LB[1][(bng * 4 + j) * 40 + bkg * 4] = lv;
        }
        __syncthreads();
        // ---- fragments + 48 MFMAs
        bf16x8 ah[4], al_[4], bh[4], bl[4];
#pragma unroll
        for (int m = 0; m < 4; m++) {
            ah[m]  = *(const bf16x8*)&LA[0][(wm + m * 16 + fr) * 40 + g * 8];
            al_[m] = *(const bf16x8*)&LA[1][(wm + m * 16 + fr) * 40 + g * 8];
        }
#pragma unroll
        for (int n = 0; n < 4; n++) {
            bh[n] = *(const bf16x8*)&LB[0][(wn + n * 16 + fr) * 40 + g * 8];
            bl[n] = *(const bf16x8*)&LB[1][(wn + n * 16 + fr) * 40 + g * 8];
        }
#pragma unroll
        for (int m = 0; m < 4; m++)
#pragma unroll
            for (int n = 0; n < 4; n++) {
                acc[m][n] = MFMA(ah[m], bh[n], acc[m][n]);
                acc[m][n] = MFMA(ah[m], bl[n], acc[m][n]);
                acc[m][n] = MFMA(al_[m], bh[n], acc[m][n]);
            }
    }
    // ---- epilogue
#pragma unroll
    for (int m = 0; m < 4; m++)
#pragma unroll
        for (int n = 0; n < 4; n++) {
            size_t col = n0 + wn + n * 16 + fr;
#pragma unroll
            for (int r = 0; r < 4; r++) {
                size_t row = m0 + wm + m * 16 + g * 4 + r;
                float v = acc[m][n][r];
                if constexpr (EPI == EPI_F32) {
                    Cf[row * N + col] = v;
                } else if constexpr (EPI == EPI_SPLIT) {
                    u16 hh = f2bf(v);
                    Oh[row * N + col] = hh;
                    Ol[row * N + col] = f2bf(v - bf2f(hh));
                } else if constexpr (EPI == EPI_GELU) {
                    v += bias[col];
                    float t  = tanhf(0.7978845608028654f * (v + 0.044715f * v * v * v));
                    float gl = 0.5f * v * (1.0f + t);
                    u16 hh = f2bf(gl);
                    Oh[row * N + col] = hh;
                    Ol[row * N + col] = f2bf(gl - bf2f(hh));
                } else { // EPI_FINAL
                    v += bias[col] + addin[row * N + col];
                    Cf[row * N + col] = v;
                }
            }
        }
}

// ---------------------------------------------------------------- flash attention
// grid (32, 16): y = head, x -> q-block (remapped for balance). QBLK=64 (16 rows/wave), KBLK=32.
__global__ __launch_bounds__(256, 2) void attn_kernel(
    const u16* __restrict__ Qh, const u16* __restrict__ Ql,
    const u16* __restrict__ Kh, const u16* __restrict__ Kl,
    const u16* __restrict__ Vh, const u16* __restrict__ Vl,
    const float* __restrict__ bias, u16* __restrict__ Oh, u16* __restrict__ Ol) {
    __shared__ __align__(16) u16 LKh[32 * 256], LKl[32 * 256];  // [t][d], 16B-slot XOR swizzle
    __shared__ __align__(16) u16 LVh[256 * 32], LVl[256 * 32];  // [d][t], 2-bit XOR swizzle
    __shared__ __align__(16) u16 LP[4][2][16 * 40];             // per-wave P hi/lo
    const int tid = threadIdx.x, lane = tid & 63, w = tid >> 6;
    const int h = blockIdx.y;
    const int qb = (h < 8) ? (int)blockIdx.x : 31 - (int)blockIdx.x;  // pairwise load balance
    const int fr = lane & 15, g = lane >> 4;
    const int q0 = qb * 64 + w * 16;
    const size_t DM = 4096;

    bf16x8 qfh[8], qfl[8];
    {
        size_t base = (size_t)(q0 + fr) * DM + (size_t)h * 256 + g * 8;
#pragma unroll
        for (int ks = 0; ks < 8; ks++) {
            qfh[ks] = *(const bf16x8*)&Qh[base + ks * 32];
            qfl[ks] = *(const bf16x8*)&Ql[base + ks * 32];
        }
    }
    f32x4 opv[16] = {};
    float mrun[4] = { -1e30f, -1e30f, -1e30f, -1e30f };
    float lrun[4] = {};
    const int nkb = 2 * qb + 2;

    for (int kb = 0; kb < nkb; kb++) {
        const int t0 = kb * 32;
        __syncthreads();
        // ---- stage K [t][d] with slot swizzle phys = slot ^ (t&7)
#pragma unroll
        for (int u = 0; u < 4; u++) {
            int id = u * 256 + tid;                 // 0..1023
            int t = id >> 5, slot = id & 31;
            size_t gs = (size_t)(t0 + t) * DM + (size_t)h * 256 + slot * 8;
            int phys = slot ^ (t & 7);
            *(u16x8*)&LKh[t * 256 + phys * 8] = *(const u16x8*)&Kh[gs];
            *(u16x8*)&LKl[t * 256 + phys * 8] = *(const u16x8*)&Kl[gs];
        }
        // ---- stage V transposed [d][t], phys = tslot ^ ((d ^ d>>2) & 3)
#pragma unroll
        for (int u = 0; u < 4; u++) {
            int id = u * 256 + tid;                 // 0..1023
            int ts = id >> 8, d = id & 255;
            u16 th[8], tl[8];
#pragma unroll
            for (int j = 0; j < 8; j++) {
                size_t gs = (size_t)(t0 + ts * 8 + j) * DM + (size_t)h * 256 + d;
                th[j] = Vh[gs];
                tl[j] = Vl[gs];
            }
            int phys = ts ^ ((d ^ (d >> 2)) & 3);
            u16x8 vh = { th[0], th[1], th[2], th[3], th[4], th[5], th[6], th[7] };
            u16x8 vl = { tl[0], tl[1], tl[2], tl[3], tl[4], tl[5], tl[6], tl[7] };
            *(u16x8*)&LVh[d * 32 + phys * 8] = vh;
            *(u16x8*)&LVl[d * 32 + phys * 8] = vl;
        }
        __syncthreads();
        // ---- QK^T (bf16x3)
        f32x4 sac[2] = {};
#pragma unroll
        for (int ks = 0; ks < 8; ks++)
#pragma unroll
            for (int nf = 0; nf < 2; nf++) {
                int t = nf * 16 + fr;
                int phys = (ks * 4 + g) ^ (t & 7);
                bf16x8 kfh = *(const bf16x8*)&LKh[t * 256 + phys * 8];
                bf16x8 kfl = *(const bf16x8*)&LKl[t * 256 + phys * 8];
                sac[nf] = MFMA(qfh[ks], kfh, sac[nf]);
                sac[nf] = MFMA(qfh[ks], kfl, sac[nf]);
                sac[nf] = MFMA(qfl[ks], kfh, sac[nf]);
            }
        // ---- online softmax (rows live on 16-lane groups; r -> q = g*4+r)
        float pvv[2][4], rmax[4];
#pragma unroll
        for (int r = 0; r < 4; r++) {
            int qrow = q0 + g * 4 + r;
            int tg0 = t0 + fr, tg1 = t0 + 16 + fr;
            float s0 = sac[0][r] * 0.0625f + bias[(size_t)qrow * 2048 + tg0] + (tg0 > qrow ? -1e10f : 0.f);
            float s1 = sac[1][r] * 0.0625f + bias[(size_t)qrow * 2048 + tg1] + (tg1 > qrow ? -1e10f : 0.f);
            pvv[0][r] = s0; pvv[1][r] = s1;
            rmax[r] = fmaxf(s0, s1);
        }
#pragma unroll
        for (int m = 1; m <= 8; m <<= 1)
#pragma unroll
            for (int r = 0; r < 4; r++) rmax[r] = fmaxf(rmax[r], __shfl_xor(rmax[r], m));
        float alpha[4], psum[4];
#pragma unroll
        for (int r = 0; r < 4; r++) {
            float mnew = fmaxf(mrun[r], rmax[r]);
            alpha[r] = expf(mrun[r] - mnew);
            mrun[r] = mnew;
            pvv[0][r] = expf(pvv[0][r] - mnew);
            pvv[1][r] = expf(pvv[1][r] - mnew);
            psum[r] = pvv[0][r] + pvv[1][r];
        }
#pragma unroll
        for (int m = 1; m <= 8; m <<= 1)
#pragma unroll
            for (int r = 0; r < 4; r++) psum[r] += __shfl_xor(psum[r], m);
#pragma unroll
        for (int r = 0; r < 4; r++) lrun[r] = lrun[r] * alpha[r] + psum[r];
#pragma unroll
        for (int nf = 0; nf < 16; nf++)
#pragma unroll
            for (int r = 0; r < 4; r++) opv[nf][r] *= alpha[r];
        // ---- P -> LDS (layout conversion C->A), split hi/lo
#pragma unroll
        for (int f = 0; f < 2; f++)
#pragma unroll
            for (int r = 0; r < 4; r++) {
                u16 ph = f2bf(pvv[f][r]);
                LP[w][0][(g * 4 + r) * 40 + f * 16 + fr] = ph;
                LP[w][1][(g * 4 + r) * 40 + f * 16 + fr] = f2bf(pvv[f][r] - bf2f(ph));
            }
        asm volatile("s_waitcnt lgkmcnt(0)" ::: "memory");
        bf16x8 pah = *(const bf16x8*)&LP[w][0][fr * 40 + g * 8];
        bf16x8 pal = *(const bf16x8*)&LP[w][1][fr * 40 + g * 8];
        // ---- P @ V (bf16x3)
#pragma unroll
        for (int nf = 0; nf < 16; nf++) {
            int d = nf * 16 + fr;
            int phys = g ^ ((d ^ (d >> 2)) & 3);
            bf16x8 vfh = *(const bf16x8*)&LVh[d * 32 + phys * 8];
            bf16x8 vfl = *(const bf16x8*)&LVl[d * 32 + phys * 8];
            opv[nf] = MFMA(pah, vfh, opv[nf]);
            opv[nf] = MFMA(pah, vfl, opv[nf]);
            opv[nf] = MFMA(pal, vfh, opv[nf]);
        }
    }
    // ---- epilogue: normalize + split write
#pragma unroll
    for (int nf = 0; nf < 16; nf++) {
        size_t col = (size_t)h * 256 + nf * 16 + fr;
#pragma unroll
        for (int r = 0; r < 4; r++) {
            size_t row = (size_t)(q0 + g * 4 + r);
            float v = opv[nf][r] / lrun[r];
            u16 hh = f2bf(v);
            Oh[row * DM + col] = hh;
            Ol[row * DM + col] = f2bf(v - bf2f(hh));
        }
    }
}

// ---------------------------------------------------------------- host
extern "C" void kernel_launch(void* const* d_in, const int* in_sizes, int n_in,
                              void* d_out, int out_size, void* d_ws, size_t ws_size,
                              hipStream_t stream) {
    const float* x        = (const float*)d_in[0];
    const float* attnbias = (const float*)d_in[1];
    const float* ln_scale = (const float*)d_in[2];
    const float* ln_off   = (const float*)d_in[3];
    const float* wq = (const float*)d_in[4];
    const float* wk = (const float*)d_in[5];
    const float* wv = (const float*)d_in[6];
    const float* wo = (const float*)d_in[7];
    const float* w1 = (const float*)d_in[8];
    const float* b1 = (const float*)d_in[9];
    const float* w2 = (const float*)d_in[10];
    const float* b2 = (const float*)d_in[11];
    float* out = (float*)d_out;

    char* ws = (char*)d_ws;
    size_t off = 0;
    auto alloc = [&](size_t bytes) -> void* {
        void* p = ws + off;
        off += (bytes + 255) & ~(size_t)255;
        return p;
    };
    const size_t SD  = (size_t)2048 * 4096;   // 8.39M elems
    const size_t SF  = (size_t)2048 * 16384;  // 33.6M elems
    u16* xnh = (u16*)alloc(SD * 2); u16* xnl = (u16*)alloc(SD * 2);
    u16* qh  = (u16*)alloc(SD * 2); u16* ql  = (u16*)alloc(SD * 2);
    u16* kh  = (u16*)alloc(SD * 2); u16* kl  = (u16*)alloc(SD * 2);
    u16* vh  = (u16*)alloc(SD * 2); u16* vl  = (u16*)alloc(SD * 2);
    u16* ath = (u16*)alloc(SD * 2); u16* atl = (u16*)alloc(SD * 2);
    u16* hh  = (u16*)alloc(SF * 2); u16* hl  = (u16*)alloc(SF * 2);
    float* stab = (float*)alloc((size_t)2048 * 32 * 4);
    float* ctab = (float*)alloc((size_t)2048 * 32 * 4);
    (void)ws_size; (void)in_sizes; (void)n_in; (void)out_size;

    sincos_kernel<<<256, 256, 0, stream>>>(stab, ctab);
    ln_kernel<<<2048, 256, 0, stream>>>(x, ln_scale, ln_off, xnh, xnl);

    dim3 g44(32, 16);   // N=4096, M=2048
    gemm_kernel<EPI_SPLIT><<<g44, 256, 0, stream>>>(xnh, xnl, wq, 2048, 4096, 4096,
                                                    nullptr, qh, ql, nullptr, nullptr);
    gemm_kernel<EPI_SPLIT><<<g44, 256, 0, stream>>>(xnh, xnl, wk, 2048, 4096, 4096,
                                                    nullptr, kh, kl, nullptr, nullptr);
    gemm_kernel<EPI_SPLIT><<<g44, 256, 0, stream>>>(xnh, xnl, wv, 2048, 4096, 4096,
                                                    nullptr, vh, vl, nullptr, nullptr);
    rope_kernel<<<4096, 256, 0, stream>>>(qh, ql, kh, kl, stab, ctab);
    attn_kernel<<<dim3(32, 16), 256, 0, stream>>>(qh, ql, kh, kl, vh, vl, attnbias, ath, atl);
    gemm_kernel<EPI_F32><<<g44, 256, 0, stream>>>(ath, atl, wo, 2048, 4096, 4096,
                                                  out, nullptr, nullptr, nullptr, nullptr);
    gemm_kernel<EPI_GELU><<<dim3(128, 16), 256, 0, stream>>>(xnh, xnl, w1, 2048, 16384, 4096,
                                                             nullptr, hh, hl, b1, nullptr);
    gemm_kernel<EPI_FINAL><<<g44, 256, 0, stream>>>(hh, hl, w2, 2048, 4096, 16384,
                                                    out, nullptr, nullptr, b2, out);
}

// Round 6
// 4102.167 us; speedup vs baseline: 1.0986x; 1.0986x over previous
//
#include <hip/hip_runtime.h>
#include <math.h>

typedef unsigned short u16;
typedef unsigned int   u32;
typedef __attribute__((ext_vector_type(8))) short bf16x8;   // 8 bf16 = 4 VGPR
typedef __attribute__((ext_vector_type(4))) float f32x4;
typedef __attribute__((ext_vector_type(4))) u16   u16x4;
typedef __attribute__((ext_vector_type(8))) u16   u16x8;

#define MFMA(a,b,c) __builtin_amdgcn_mfma_f32_16x16x32_bf16((a),(b),(c),0,0,0)

__device__ __forceinline__ u16 f2bf(float f) {
    u32 u = __float_as_uint(f);
    u32 r = (u + 0x7fffu + ((u >> 16) & 1u)) >> 16;   // RNE
    return (u16)r;
}
__device__ __forceinline__ float bf2f(u16 h) { return __uint_as_float(((u32)h) << 16); }

__device__ __forceinline__ void gload_lds16(const void* g, void* l) {
    __builtin_amdgcn_global_load_lds(
        (const __attribute__((address_space(1))) void*)g,
        (__attribute__((address_space(3))) void*)l, 16, 0, 0);
}

// ---------------------------------------------------------------- sincos table
__global__ void sincos_kernel(float* __restrict__ st, float* __restrict__ ct) {
    int idx = blockIdx.x * 256 + threadIdx.x;      // 2048*32
    int t = idx >> 5, j = idx & 31;
    double inv = pow(10000.0, -(double)j / 32.0);
    double a = (double)t * inv;
    st[idx] = (float)sin(a);
    ct[idx] = (float)cos(a);
}

// ---------------------------------------------------------------- layernorm + split
__global__ __launch_bounds__(256) void ln_kernel(
    const float* __restrict__ x, const float* __restrict__ sc,
    const float* __restrict__ ofs, u16* __restrict__ Oh, u16* __restrict__ Ol) {
    const int row = blockIdx.x, tid = threadIdx.x;
    const float* xr = x + (size_t)row * 4096;
    float4 v[4];
    float s1 = 0.f, s2 = 0.f;
#pragma unroll
    for (int i = 0; i < 4; i++) {
        v[i] = *(const float4*)&xr[i * 1024 + tid * 4];
        s1 += v[i].x + v[i].y + v[i].z + v[i].w;
        s2 += v[i].x * v[i].x + v[i].y * v[i].y + v[i].z * v[i].z + v[i].w * v[i].w;
    }
#pragma unroll
    for (int m = 1; m < 64; m <<= 1) { s1 += __shfl_xor(s1, m); s2 += __shfl_xor(s2, m); }
    __shared__ float red[8];
    int w = tid >> 6;
    if ((tid & 63) == 0) { red[w] = s1; red[4 + w] = s2; }
    __syncthreads();
    s1 = red[0] + red[1] + red[2] + red[3];
    s2 = red[4] + red[5] + red[6] + red[7];
    float mean = s1 * (1.0f / 4096.0f);
    float var  = s2 * (1.0f / 4096.0f) - mean * mean;
    float rs   = 1.0f / sqrtf(var + 1e-5f);
#pragma unroll
    for (int i = 0; i < 4; i++) {
        int c0 = i * 1024 + tid * 4;
        float xs[4] = { v[i].x, v[i].y, v[i].z, v[i].w };
        u16x4 hv, lv;
#pragma unroll
        for (int j = 0; j < 4; j++) {
            float xn = sc[c0 + j] * rs * (xs[j] - mean) + ofs[c0 + j];
            u16 hh = f2bf(xn);
            hv[j] = hh;
            lv[j] = f2bf(xn - bf2f(hh));
        }
        *(u16x4*)&Oh[(size_t)row * 4096 + c0] = hv;
        *(u16x4*)&Ol[(size_t)row * 4096 + c0] = lv;
    }
}

// ---------------------------------------------------------------- rope (in-place on split q,k)
// 2048 rows * 16 heads * 32 rotated pairs = 1,048,576 threads
__global__ __launch_bounds__(256) void rope_kernel(
    u16* __restrict__ qh, u16* __restrict__ ql, u16* __restrict__ kh, u16* __restrict__ kl,
    const float* __restrict__ st, const float* __restrict__ ct) {
    int gid = blockIdx.x * 256 + threadIdx.x;
    int t  = gid >> 9;                 // row
    int hh_ = (gid >> 5) & 15;         // head
    int j2 = gid & 31;                 // rotated pair within head
    size_t base = (size_t)t * 4096 + (size_t)hh_ * 256 + (size_t)j2 * 2;
    float s = st[t * 32 + j2], c = ct[t * 32 + j2];
    {
        float x1 = bf2f(qh[base]) + bf2f(ql[base]);
        float x2 = bf2f(qh[base + 1]) + bf2f(ql[base + 1]);
        float o1 = x1 * c - x2 * s, o2 = x2 * c + x1 * s;
        u16 h1 = f2bf(o1); qh[base] = h1;     ql[base] = f2bf(o1 - bf2f(h1));
        u16 h2 = f2bf(o2); qh[base + 1] = h2; ql[base + 1] = f2bf(o2 - bf2f(h2));
    }
    {
        float x1 = bf2f(kh[base]) + bf2f(kl[base]);
        float x2 = bf2f(kh[base + 1]) + bf2f(kl[base + 1]);
        float o1 = x1 * c - x2 * s, o2 = x2 * c + x1 * s;
        u16 h1 = f2bf(o1); kh[base] = h1;     kl[base] = f2bf(o1 - bf2f(h1));
        u16 h2 = f2bf(o2); kh[base + 1] = h2; kl[base + 1] = f2bf(o2 - bf2f(h2));
    }
}

// ---------------------------------------------------------------- GEMM (bf16x3 split, 128x128 tile)
// A: M x K as hi/lo bf16 (pre-split), staged via global_load_lds into linear [128][32].
// B: K x N f32, split on the fly, stored n-major in XOR-swizzled 16B slots:
//   physS(n,slot) = (n*4+slot) ^ ((n>>2)&3) ^ (((n>>4)&1)<<2)   [bijective; both sides use it]
enum { EPI_F32 = 0, EPI_SPLIT = 1, EPI_GELU = 2, EPI_FINAL = 3 };

template <int EPI>
__global__ __launch_bounds__(256, 4) void gemm_kernel(
    const u16* __restrict__ Ah, const u16* __restrict__ Al,
    const float* __restrict__ B, int M, int N, int K,
    float* __restrict__ Cf, u16* __restrict__ Oh, u16* __restrict__ Ol,
    const float* __restrict__ bias, const float* __restrict__ addin) {
    __shared__ __align__(16) u16 LA[2][128 * 32];   // linear [row][k] (gload_lds dest)
    __shared__ __align__(16) u16 LB[2][128 * 32];   // [n][k] via swizzled 16B slots
    const int tid = threadIdx.x;
    const int lane = tid & 63, w = tid >> 6;
    const int wm = (w >> 1) * 64, wn = (w & 1) * 64;
    const size_t n0 = (size_t)blockIdx.x * 128, m0 = (size_t)blockIdx.y * 128;
    const int fr = lane & 15, g = lane >> 4;
    const int bkg = tid >> 5, bng = tid & 31;       // B staging: k-group(8 of 4), n-group(32 of 4)

    // ---- precomputed loop-invariant LDS offsets (u16 units)
    int roffA[4], roffB[4], woffB[4];
#pragma unroll
    for (int m = 0; m < 4; m++)
        roffA[m] = (wm + m * 16 + fr) * 32 + g * 8;
    const int bslot = g ^ ((fr >> 2) & 3);
#pragma unroll
    for (int nf = 0; nf < 4; nf++) {
        int n = wn + nf * 16 + fr;
        int physS = ((n * 4 + bslot)) ^ ((nf & 1) << 2);   // (n>>2)&3 folded into bslot; (n>>4)&1 == nf&1
        roffB[nf] = physS * 8;
    }
#pragma unroll
    for (int j = 0; j < 4; j++) {
        int n = bng * 4 + j;
        int physS = (n * 4 + ((bkg >> 1) ^ (bng & 3))) ^ (((bng >> 2) & 1) << 2);
        woffB[j] = physS * 8 + (bkg & 1) * 4;
    }
    // A gload geometry: wave w stages rows [w*32, w*32+32); 2 insts x 1024B per buffer
    const int arow = lane >> 2, aslot = lane & 3;

    f32x4 acc[4][4] = {};

    for (int k0 = 0; k0 < K; k0 += 32) {
        __syncthreads();
        // ---- stage A via global_load_lds (16B/lane, linear dest)
#pragma unroll
        for (int p = 0; p < 2; p++) {
            int rbase = w * 32 + p * 16;
            size_t gs = (m0 + rbase + arow) * (size_t)K + k0 + aslot * 8;
            gload_lds16(&Ah[gs], &LA[0][rbase * 32]);
            gload_lds16(&Al[gs], &LA[1][rbase * 32]);
        }
        // ---- stage B: 4x4 micro-tile, f32 -> hi/lo, transpose to swizzled n-major
        float4 rv[4];
#pragma unroll
        for (int i = 0; i < 4; i++)
            rv[i] = *(const float4*)&B[(size_t)(k0 + bkg * 4 + i) * N + n0 + bng * 4];
#pragma unroll
        for (int j = 0; j < 4; j++) {
            float v0 = (&rv[0].x)[j], v1 = (&rv[1].x)[j], v2 = (&rv[2].x)[j], v3 = (&rv[3].x)[j];
            u16 h0 = f2bf(v0), h1 = f2bf(v1), h2 = f2bf(v2), h3 = f2bf(v3);
            u16x4 hv = { h0, h1, h2, h3 };
            u16x4 lv = { f2bf(v0 - bf2f(h0)), f2bf(v1 - bf2f(h1)),
                         f2bf(v2 - bf2f(h2)), f2bf(v3 - bf2f(h3)) };
            *(u16x4*)&LB[0][woffB[j]] = hv;
            *(u16x4*)&LB[1][woffB[j]] = lv;
        }
        __syncthreads();
        // ---- fragments + 48 MFMAs
        bf16x8 ah[4], al_[4], bh[4], bl[4];
#pragma unroll
        for (int m = 0; m < 4; m++) {
            ah[m]  = *(const bf16x8*)&LA[0][roffA[m]];
            al_[m] = *(const bf16x8*)&LA[1][roffA[m]];
        }
#pragma unroll
        for (int n = 0; n < 4; n++) {
            bh[n] = *(const bf16x8*)&LB[0][roffB[n]];
            bl[n] = *(const bf16x8*)&LB[1][roffB[n]];
        }
#pragma unroll
        for (int m = 0; m < 4; m++)
#pragma unroll
            for (int n = 0; n < 4; n++) {
                acc[m][n] = MFMA(ah[m], bh[n], acc[m][n]);
                acc[m][n] = MFMA(ah[m], bl[n], acc[m][n]);
                acc[m][n] = MFMA(al_[m], bh[n], acc[m][n]);
            }
    }
    // ---- epilogue
#pragma unroll
    for (int m = 0; m < 4; m++)
#pragma unroll
        for (int n = 0; n < 4; n++) {
            size_t col = n0 + wn + n * 16 + fr;
#pragma unroll
            for (int r = 0; r < 4; r++) {
                size_t row = m0 + wm + m * 16 + g * 4 + r;
                float v = acc[m][n][r];
                if constexpr (EPI == EPI_F32) {
                    Cf[row * N + col] = v;
                } else if constexpr (EPI == EPI_SPLIT) {
                    u16 hh = f2bf(v);
                    Oh[row * N + col] = hh;
                    Ol[row * N + col] = f2bf(v - bf2f(hh));
                } else if constexpr (EPI == EPI_GELU) {
                    v += bias[col];
                    float t  = tanhf(0.7978845608028654f * (v + 0.044715f * v * v * v));
                    float gl = 0.5f * v * (1.0f + t);
                    u16 hh = f2bf(gl);
                    Oh[row * N + col] = hh;
                    Ol[row * N + col] = f2bf(gl - bf2f(hh));
                } else { // EPI_FINAL
                    v += bias[col] + addin[row * N + col];
                    Cf[row * N + col] = v;
                }
            }
        }
}

// ---------------------------------------------------------------- flash attention
// grid (32, 16): y = head, x -> q-block (remapped for balance). QBLK=64 (16 rows/wave), KBLK=32.
__global__ __launch_bounds__(256, 2) void attn_kernel(
    const u16* __restrict__ Qh, const u16* __restrict__ Ql,
    const u16* __restrict__ Kh, const u16* __restrict__ Kl,
    const u16* __restrict__ Vh, const u16* __restrict__ Vl,
    const float* __restrict__ bias, u16* __restrict__ Oh, u16* __restrict__ Ol) {
    __shared__ __align__(16) u16 LKh[32 * 256], LKl[32 * 256];  // [t][d], 16B-slot XOR swizzle
    __shared__ __align__(16) u16 LVh[256 * 32], LVl[256 * 32];  // [d][t], 2-bit XOR swizzle
    __shared__ __align__(16) u16 LP[4][2][16 * 40];             // per-wave P hi/lo
    const int tid = threadIdx.x, lane = tid & 63, w = tid >> 6;
    const int h = blockIdx.y;
    const int qb = (h < 8) ? (int)blockIdx.x : 31 - (int)blockIdx.x;  // pairwise load balance
    const int fr = lane & 15, g = lane >> 4;
    const int q0 = qb * 64 + w * 16;
    const size_t DM = 4096;

    bf16x8 qfh[8], qfl[8];
    {
        size_t base = (size_t)(q0 + fr) * DM + (size_t)h * 256 + g * 8;
#pragma unroll
        for (int ks = 0; ks < 8; ks++) {
            qfh[ks] = *(const bf16x8*)&Qh[base + ks * 32];
            qfl[ks] = *(const bf16x8*)&Ql[base + ks * 32];
        }
    }
    f32x4 opv[16] = {};
    float mrun[4] = { -1e30f, -1e30f, -1e30f, -1e30f };
    float lrun[4] = {};
    const int nkb = 2 * qb + 2;

    for (int kb = 0; kb < nkb; kb++) {
        const int t0 = kb * 32;
        __syncthreads();
        // ---- stage K [t][d] with slot swizzle phys = slot ^ (t&7)
#pragma unroll
        for (int u = 0; u < 4; u++) {
            int id = u * 256 + tid;                 // 0..1023
            int t = id >> 5, slot = id & 31;
            size_t gs = (size_t)(t0 + t) * DM + (size_t)h * 256 + slot * 8;
            int phys = slot ^ (t & 7);
            *(u16x8*)&LKh[t * 256 + phys * 8] = *(const u16x8*)&Kh[gs];
            *(u16x8*)&LKl[t * 256 + phys * 8] = *(const u16x8*)&Kl[gs];
        }
        // ---- stage V transposed [d][t], phys = tslot ^ ((d ^ d>>2) & 3)
#pragma unroll
        for (int u = 0; u < 4; u++) {
            int id = u * 256 + tid;                 // 0..1023
            int ts = id >> 8, d = id & 255;
            u16 th[8], tl[8];
#pragma unroll
            for (int j = 0; j < 8; j++) {
                size_t gs = (size_t)(t0 + ts * 8 + j) * DM + (size_t)h * 256 + d;
                th[j] = Vh[gs];
                tl[j] = Vl[gs];
            }
            int phys = ts ^ ((d ^ (d >> 2)) & 3);
            u16x8 vh = { th[0], th[1], th[2], th[3], th[4], th[5], th[6], th[7] };
            u16x8 vl = { tl[0], tl[1], tl[2], tl[3], tl[4], tl[5], tl[6], tl[7] };
            *(u16x8*)&LVh[d * 32 + phys * 8] = vh;
            *(u16x8*)&LVl[d * 32 + phys * 8] = vl;
        }
        __syncthreads();
        // ---- QK^T (bf16x3)
        f32x4 sac[2] = {};
#pragma unroll
        for (int ks = 0; ks < 8; ks++)
#pragma unroll
            for (int nf = 0; nf < 2; nf++) {
                int t = nf * 16 + fr;
                int phys = (ks * 4 + g) ^ (t & 7);
                bf16x8 kfh = *(const bf16x8*)&LKh[t * 256 + phys * 8];
                bf16x8 kfl = *(const bf16x8*)&LKl[t * 256 + phys * 8];
                sac[nf] = MFMA(qfh[ks], kfh, sac[nf]);
                sac[nf] = MFMA(qfh[ks], kfl, sac[nf]);
                sac[nf] = MFMA(qfl[ks], kfh, sac[nf]);
            }
        // ---- online softmax (rows live on 16-lane groups; r -> q = g*4+r)
        float pvv[2][4], rmax[4];
#pragma unroll
        for (int r = 0; r < 4; r++) {
            int qrow = q0 + g * 4 + r;
            int tg0 = t0 + fr, tg1 = t0 + 16 + fr;
            float s0 = sac[0][r] * 0.0625f + bias[(size_t)qrow * 2048 + tg0] + (tg0 > qrow ? -1e10f : 0.f);
            float s1 = sac[1][r] * 0.0625f + bias[(size_t)qrow * 2048 + tg1] + (tg1 > qrow ? -1e10f : 0.f);
            pvv[0][r] = s0; pvv[1][r] = s1;
            rmax[r] = fmaxf(s0, s1);
        }
#pragma unroll
        for (int m = 1; m <= 8; m <<= 1)
#pragma unroll
            for (int r = 0; r < 4; r++) rmax[r] = fmaxf(rmax[r], __shfl_xor(rmax[r], m));
        float alpha[4], psum[4];
#pragma unroll
        for (int r = 0; r < 4; r++) {
            float mnew = fmaxf(mrun[r], rmax[r]);
            alpha[r] = expf(mrun[r] - mnew);
            mrun[r] = mnew;
            pvv[0][r] = expf(pvv[0][r] - mnew);
            pvv[1][r] = expf(pvv[1][r] - mnew);
            psum[r] = pvv[0][r] + pvv[1][r];
        }
#pragma unroll
        for (int m = 1; m <= 8; m <<= 1)
#pragma unroll
            for (int r = 0; r < 4; r++) psum[r] += __shfl_xor(psum[r], m);
#pragma unroll
        for (int r = 0; r < 4; r++) lrun[r] = lrun[r] * alpha[r] + psum[r];
#pragma unroll
        for (int nf = 0; nf < 16; nf++)
#pragma unroll
            for (int r = 0; r < 4; r++) opv[nf][r] *= alpha[r];
        // ---- P -> LDS (layout conversion C->A), split hi/lo
#pragma unroll
        for (int f = 0; f < 2; f++)
#pragma unroll
            for (int r = 0; r < 4; r++) {
                u16 ph = f2bf(pvv[f][r]);
                LP[w][0][(g * 4 + r) * 40 + f * 16 + fr] = ph;
                LP[w][1][(g * 4 + r) * 40 + f * 16 + fr] = f2bf(pvv[f][r] - bf2f(ph));
            }
        asm volatile("s_waitcnt lgkmcnt(0)" ::: "memory");
        bf16x8 pah = *(const bf16x8*)&LP[w][0][fr * 40 + g * 8];
        bf16x8 pal = *(const bf16x8*)&LP[w][1][fr * 40 + g * 8];
        // ---- P @ V (bf16x3)
#pragma unroll
        for (int nf = 0; nf < 16; nf++) {
            int d = nf * 16 + fr;
            int phys = g ^ ((d ^ (d >> 2)) & 3);
            bf16x8 vfh = *(const bf16x8*)&LVh[d * 32 + phys * 8];
            bf16x8 vfl = *(const bf16x8*)&LVl[d * 32 + phys * 8];
            opv[nf] = MFMA(pah, vfh, opv[nf]);
            opv[nf] = MFMA(pah, vfl, opv[nf]);
            opv[nf] = MFMA(pal, vfh, opv[nf]);
        }
    }
    // ---- epilogue: normalize + split write
#pragma unroll
    for (int nf = 0; nf < 16; nf++) {
        size_t col = (size_t)h * 256 + nf * 16 + fr;
#pragma unroll
        for (int r = 0; r < 4; r++) {
            size_t row = (size_t)(q0 + g * 4 + r);
            float v = opv[nf][r] / lrun[r];
            u16 hh = f2bf(v);
            Oh[row * DM + col] = hh;
            Ol[row * DM + col] = f2bf(v - bf2f(hh));
        }
    }
}

// ---------------------------------------------------------------- host
extern "C" void kernel_launch(void* const* d_in, const int* in_sizes, int n_in,
                              void* d_out, int out_size, void* d_ws, size_t ws_size,
                              hipStream_t stream) {
    const float* x        = (const float*)d_in[0];
    const float* attnbias = (const float*)d_in[1];
    const float* ln_scale = (const float*)d_in[2];
    const float* ln_off   = (const float*)d_in[3];
    const float* wq = (const float*)d_in[4];
    const float* wk = (const float*)d_in[5];
    const float* wv = (const float*)d_in[6];
    const float* wo = (const float*)d_in[7];
    const float* w1 = (const float*)d_in[8];
    const float* b1 = (const float*)d_in[9];
    const float* w2 = (const float*)d_in[10];
    const float* b2 = (const float*)d_in[11];
    float* out = (float*)d_out;

    char* ws = (char*)d_ws;
    size_t off = 0;
    auto alloc = [&](size_t bytes) -> void* {
        void* p = ws + off;
        off += (bytes + 255) & ~(size_t)255;
        return p;
    };
    const size_t SD  = (size_t)2048 * 4096;   // 8.39M elems
    const size_t SF  = (size_t)2048 * 16384;  // 33.6M elems
    u16* xnh = (u16*)alloc(SD * 2); u16* xnl = (u16*)alloc(SD * 2);
    u16* qh  = (u16*)alloc(SD * 2); u16* ql  = (u16*)alloc(SD * 2);
    u16* kh  = (u16*)alloc(SD * 2); u16* kl  = (u16*)alloc(SD * 2);
    u16* vh  = (u16*)alloc(SD * 2); u16* vl  = (u16*)alloc(SD * 2);
    u16* ath = (u16*)alloc(SD * 2); u16* atl = (u16*)alloc(SD * 2);
    u16* hh  = (u16*)alloc(SF * 2); u16* hl  = (u16*)alloc(SF * 2);
    float* stab = (float*)alloc((size_t)2048 * 32 * 4);
    float* ctab = (float*)alloc((size_t)2048 * 32 * 4);
    (void)ws_size; (void)in_sizes; (void)n_in; (void)out_size;

    sincos_kernel<<<256, 256, 0, stream>>>(stab, ctab);
    ln_kernel<<<2048, 256, 0, stream>>>(x, ln_scale, ln_off, xnh, xnl);

    dim3 g44(32, 16);   // N=4096, M=2048
    gemm_kernel<EPI_SPLIT><<<g44, 256, 0, stream>>>(xnh, xnl, wq, 2048, 4096, 4096,
                                                    nullptr, qh, ql, nullptr, nullptr);
    gemm_kernel<EPI_SPLIT><<<g44, 256, 0, stream>>>(xnh, xnl, wk, 2048, 4096, 4096,
                                                    nullptr, kh, kl, nullptr, nullptr);
    gemm_kernel<EPI_SPLIT><<<g44, 256, 0, stream>>>(xnh, xnl, wv, 2048, 4096, 4096,
                                                    nullptr, vh, vl, nullptr, nullptr);
    rope_kernel<<<4096, 256, 0, stream>>>(qh, ql, kh, kl, stab, ctab);
    attn_kernel<<<dim3(32, 16), 256, 0, stream>>>(qh, ql, kh, kl, vh, vl, attnbias, ath, atl);
    gemm_kernel<EPI_F32><<<g44, 256, 0, stream>>>(ath, atl, wo, 2048, 4096, 4096,
                                                  out, nullptr, nullptr, nullptr, nullptr);
    gemm_kernel<EPI_GELU><<<dim3(128, 16), 256, 0, stream>>>(xnh, xnl, w1, 2048, 16384, 4096,
                                                             nullptr, hh, hl, b1, nullptr);
    gemm_kernel<EPI_FINAL><<<g44, 256, 0, stream>>>(hh, hl, w2, 2048, 4096, 16384,
                                                    out, nullptr, nullptr, b2, out);
}